// Round 3
// baseline (155.355 us; speedup 1.0000x reference)
//
#include <hip/hip_runtime.h>

// ---- problem constants ----
#define Bb 32     // batch
#define NN 1024   // H*W = K dim = output cols per channel
#define CC 128    // channels
#define KS 64     // K step per LDS stage
#define MT 128    // m-cols per block (4 waves x 32)
#define NSTEP (NN / KS)  // 16

typedef __bf16 bf16x8 __attribute__((ext_vector_type(8)));
typedef __bf16 bf16x4 __attribute__((ext_vector_type(4)));
typedef float f32x16 __attribute__((ext_vector_type(16)));
typedef float f32x4 __attribute__((ext_vector_type(4)));
typedef unsigned short u16x8 __attribute__((ext_vector_type(8)));

// ---------------------------------------------------------------------------
// Pre-pass: inputs [B, N, C] fp32 -> xbf [C, B, N] bf16 (coalesced both sides
// via LDS tile). 512 blocks = 32 b x 16 n-tiles of 64.
// ---------------------------------------------------------------------------
__global__ __launch_bounds__(256) void transpose_x(const float* __restrict__ in,
                                                   __bf16* __restrict__ xbf) {
    __shared__ float tile[64 * 132];  // 64 n x 128 c, row padded to 132 floats
    const int b  = blockIdx.x >> 4;
    const int n0 = (blockIdx.x & 15) << 6;
    const int t  = threadIdx.x;

#pragma unroll
    for (int p = 0; p < 8; ++p) {
        int f     = p * 256 + t;
        int n_off = f >> 5;
        int c4    = (f & 31) << 2;
        f32x4 v = *reinterpret_cast<const f32x4*>(in + ((size_t)(b * NN + n0 + n_off) * CC + c4));
        *reinterpret_cast<f32x4*>(&tile[n_off * 132 + c4]) = v;
    }
    __syncthreads();

    const int c = t >> 1, half = t & 1;
    const size_t obase = ((size_t)c * Bb + b) * NN + n0;
#pragma unroll
    for (int q = 0; q < 4; ++q) {
        int nb = half * 32 + q * 8;
        bf16x8 o;
#pragma unroll
        for (int j = 0; j < 8; ++j) o[j] = (__bf16)tile[(nb + j) * 132 + c];
        *reinterpret_cast<bf16x8*>(xbf + obase + nb) = o;
    }
}

// ---------------------------------------------------------------------------
// Main GEMM: block = (channel c, m-tile of 128). 4 waves, each owns 32 m cols.
// D[b=32][m=32] += A[b][k] * B[k][m] via v_mfma_f32_32x32x16_bf16.
//
// Pipeline (1 raw s_barrier per K-step, loads live ACROSS barriers):
//   LDS double-buffered (lds0/lds1, 16 KB each). Per step:
//     store W-tile (s+1) regs->LDS[other]   (compiler waits own vmcnt only)
//     issue A-frag loads (s+1), issue W-tile loads (s+2)
//     MFMA from LDS[cur]                    (waits lgkm + vmcnt(12), non-drain)
//     s_waitcnt lgkmcnt(0); s_barrier       (NO vmcnt drain -- key vs __syncthreads)
// ---------------------------------------------------------------------------
template <int USE_XBF>
__global__ __launch_bounds__(256, 4) void cwdense(const float* __restrict__ W,
                                                  const float* __restrict__ bias,
                                                  const float* __restrict__ xin,
                                                  const __bf16* __restrict__ xbf,
                                                  float* __restrict__ out) {
    __shared__ __bf16 lds0[MT * 64];  // 16 KB each; [m][kk] swizzled
    __shared__ __bf16 lds1[MT * 64];

    // XCD-friendly mapping: XCD x handles c in [16x,16x+16); consecutive i ->
    // consecutive c -> consecutive output channels merge in one XCD's L2.
    const int x     = blockIdx.x;
    const int xcd   = x & 7;
    const int i     = x >> 3;
    const int c     = xcd * 16 + (i & 15);
    const int mtile = i >> 4;
    const int m0    = mtile * MT;

    const int t    = threadIdx.x;
    const int w    = t >> 6;
    const int lane = t & 63;
    const int lm   = lane & 31;   // A row (b) / B col (m) within tile
    const int lh   = lane >> 5;   // k half
    const int m_loc = w * 32 + lm;

    const float* wpanel = W + (size_t)c * NN * NN + m0;
    const __bf16* xrow  = USE_XBF ? (xbf + (size_t)(c * Bb + lm) * NN) : nullptr;

    const int mq  = t & 31;    // m quad: cols mq*4..mq*4+3
    const int kq2 = t >> 5;    // kk quads 2*kq2, 2*kq2+1

    f32x16 acc;
#pragma unroll
    for (int r = 0; r < 16; ++r) acc[r] = 0.0f;

    f32x4 q[8];        // single W staging buffer (consumed 1 step after issue)
    bf16x8 afA[4], afB[4];

    auto load_tile = [&](int k0) {
#pragma unroll
        for (int r = 0; r < 8; ++r) {
            const int kk = (kq2 * 2 + (r >> 2)) * 4 + (r & 3);
            q[r] = *reinterpret_cast<const f32x4*>(wpanel + (size_t)(k0 + kk) * NN + mq * 4);
        }
    };

    auto store_tile = [&](__bf16* wl) {
#pragma unroll
        for (int qi = 0; qi < 2; ++qi) {
            const int kkbase = (kq2 * 2 + qi) * 4;
#pragma unroll
            for (int j = 0; j < 4; ++j) {
                const int m = mq * 4 + j;
                bf16x4 o;
#pragma unroll
                for (int r = 0; r < 4; ++r) o[r] = (__bf16)q[qi * 4 + r][j];
                const int slot = (kkbase >> 3) ^ (m & 7) ^ ((m >> 3) & 7);
                *reinterpret_cast<bf16x4*>(&wl[m * 64 + slot * 8 + (kkbase & 7)]) = o;
            }
        }
    };

    auto load_a = [&](bf16x8 (&af)[4], int k0) {
        if (USE_XBF) {
#pragma unroll
            for (int mi = 0; mi < 4; ++mi)
                af[mi] = *reinterpret_cast<const bf16x8*>(xrow + k0 + mi * 16 + lh * 8);
        } else {
#pragma unroll
            for (int mi = 0; mi < 4; ++mi) {
                u16x8 tmp;
#pragma unroll
                for (int e = 0; e < 8; ++e) {
                    float f = xin[((size_t)lm * NN + (k0 + mi * 16 + lh * 8 + e)) * CC + c];
                    unsigned u = __builtin_bit_cast(unsigned, f);
                    u = (u + 0x7FFFu + ((u >> 16) & 1u)) >> 16;
                    tmp[e] = (unsigned short)u;
                }
                af[mi] = __builtin_bit_cast(bf16x8, tmp);
            }
        }
    };

    auto mfma_step = [&](const __bf16* wl, const bf16x8 (&af)[4]) {
#pragma unroll
        for (int mi = 0; mi < 4; ++mi) {
            const int kk = mi * 16 + lh * 8;
            const int slot = (kk >> 3) ^ (m_loc & 7) ^ ((m_loc >> 3) & 7);
            bf16x8 bfrag = *reinterpret_cast<const bf16x8*>(&wl[m_loc * 64 + slot * 8]);
            acc = __builtin_amdgcn_mfma_f32_32x32x16_bf16(af[mi], bfrag, acc, 0, 0, 0);
        }
    };

#define LGKM0_BARRIER()                                       \
    asm volatile("s_waitcnt lgkmcnt(0)" ::: "memory");        \
    __builtin_amdgcn_s_barrier()

    // prologue: tile0 -> lds0; A(0) -> afA; tile1 in flight in q
    load_tile(0);
    store_tile(lds0);
    load_a(afA, 0);
    load_tile(1 * KS);
    LGKM0_BARRIER();

#pragma unroll 1
    for (int s = 0; s < NSTEP; s += 2) {
        // even step s: read lds0 (tile s), q holds tile s+1
        store_tile(lds1);                                  // vmcnt waits q only
        load_a(afB, (s + 1) * KS);                         // A for odd step
        if (s + 2 < NSTEP) load_tile((s + 2) * KS);        // W tile s+2
        mfma_step(lds0, afA);                              // overlaps in-flight loads
        LGKM0_BARRIER();

        // odd step s+1: read lds1 (tile s+1), q holds tile s+2
        if (s + 2 < NSTEP) {
            store_tile(lds0);
            load_a(afA, (s + 2) * KS);
            if (s + 3 < NSTEP) load_tile((s + 3) * KS);
        }
        mfma_step(lds1, afB);
        LGKM0_BARRIER();
    }
#undef LGKM0_BARRIER

    // epilogue: bias + relu + store. out[b][m][co], co = 127 - c.
    const int m  = m0 + m_loc;
    const float bv = bias[(size_t)c * NN + m];
    const int co = (CC - 1) - c;
#pragma unroll
    for (int r = 0; r < 16; ++r) {
        const int brow = (r & 3) + 8 * (r >> 2) + 4 * lh;
        float v = acc[r] + bv;
        v = v > 0.0f ? v : 0.0f;
        out[(size_t)brow * (NN * CC) + (size_t)m * CC + co] = v;
    }
}

extern "C" void kernel_launch(void* const* d_in, const int* in_sizes, int n_in,
                              void* d_out, int out_size, void* d_ws, size_t ws_size,
                              hipStream_t stream) {
    const float* xinp = (const float*)d_in[0];
    const float* W    = (const float*)d_in[1];
    const float* bias = (const float*)d_in[2];
    float* out        = (float*)d_out;

    const size_t need = (size_t)CC * Bb * NN * sizeof(__bf16);  // 8 MB
    if (ws_size >= need) {
        __bf16* xbf = (__bf16*)d_ws;
        transpose_x<<<512, 256, 0, stream>>>(xinp, xbf);
        cwdense<1><<<1024, 256, 0, stream>>>(W, bias, xinp, xbf, out);
    } else {
        cwdense<0><<<1024, 256, 0, stream>>>(W, bias, xinp, nullptr, out);
    }
}